// Round 5
// baseline (789.748 us; speedup 1.0000x reference)
//
#include <hip/hip_runtime.h>
#include <hip/hip_fp16.h>

// Output layout (flat): forces[n_atoms*3] | virial[n_images*9] | stress[n_images*9]
//
// v11 (resubmit -- round 4 was an infra failure, no kernel verdict):
// v10 showed direct scattered stores thrash L2 (active write-set
// 12.8 MB/XCD > 4 MB L2 -> WRITE_SIZE 370 MB vs 104 ideal). Restore v8's
// chunked LDS staging + bucket-sorted coalesced copy-out (which wrote at
// ~ideal bytes), but with: (a) uint2 8B entries, (b) virial via native
// ds_add (unsafeAtomicAdd on LDS floats -- v10 proved this is ~free),
// (c) per-block virial partials -> k_vreduce plain stores (no atomic tail).

typedef unsigned int uint;
typedef unsigned short ushort;

#define SLICES  512         // count/scatter blocks (1024 threads each)
#define BASHIFT 8           // 256 atoms per bucket
#define NBCAP   1024        // max buckets (n_atoms <= 256k)
#define NVMAX   1152        // n_images*9 cap
#define CHUNK_E 2048        // edges per sort-chunk => 4096 entries
#define CHUNK_ENT (2*CHUNK_E)
#define GT      512         // gather block size
#define GW      (GT/64)     // gather waves per block

__device__ __forceinline__ uint pack_h2(float a, float b) {
    const __half2 h = __floats2half2_rn(a, b);
    return *(const uint*)&h;
}

// ---------------- K1: per-(slice,bucket) histogram ----------------
__global__ __launch_bounds__(1024) void k_count(
    const int2* __restrict__ edge_idx, uint* __restrict__ counts,
    int n_edges, int es, int nb)
{
    __shared__ uint hist[NBCAP];
    for (int t = threadIdx.x; t < nb; t += blockDim.x) hist[t] = 0;
    __syncthreads();
    const int s  = blockIdx.x;
    const int e0 = s * es;
    const int e1 = min(n_edges, e0 + es);
    for (int e = e0 + threadIdx.x; e < e1; e += blockDim.x) {
        const int2 ij = edge_idx[e];
        atomicAdd(&hist[((uint)ij.x) >> BASHIFT], 1u);
        atomicAdd(&hist[((uint)ij.y) >> BASHIFT], 1u);
    }
    __syncthreads();
    for (int b = threadIdx.x; b < nb; b += blockDim.x)
        counts[(size_t)b * SLICES + s] = hist[b];   // bucket-major
}

// ---------------- K2a: row sums ----------------
__global__ __launch_bounds__(SLICES) void k_rowsum(
    const uint* __restrict__ counts, uint* __restrict__ rowsum)
{
    __shared__ uint red[SLICES];
    const int b = blockIdx.x;
    red[threadIdx.x] = counts[(size_t)b * SLICES + threadIdx.x];
    __syncthreads();
    for (int off = SLICES / 2; off > 0; off >>= 1) {
        if (threadIdx.x < off) red[threadIdx.x] += red[threadIdx.x + off];
        __syncthreads();
    }
    if (threadIdx.x == 0) rowsum[b] = red[0];
}

// ---------------- K2b: exclusive scan of row sums ----------------
__global__ __launch_bounds__(1024) void k_scan_rows(
    const uint* __restrict__ rowsum, uint* __restrict__ rowoff, int nb)
{
    __shared__ uint psum[1024];
    const int t = threadIdx.x;
    psum[t] = (t < nb) ? rowsum[t] : 0u;
    __syncthreads();
    for (int off = 1; off < 1024; off <<= 1) {
        uint v = (t >= off) ? psum[t - off] : 0u;
        __syncthreads();
        psum[t] += v;
        __syncthreads();
    }
    if (t < nb) rowoff[t] = (t == 0) ? 0u : psum[t - 1];
}

// ---------------- K2c: per-row exclusive scan + global offset ----------
__global__ __launch_bounds__(SLICES) void k_rowscan(
    uint* __restrict__ counts, const uint* __restrict__ rowoff)
{
    __shared__ uint psum[SLICES];
    const int b = blockIdx.x;
    const int t = threadIdx.x;
    const uint c = counts[(size_t)b * SLICES + t];
    psum[t] = c;
    __syncthreads();
    for (int off = 1; off < SLICES; off <<= 1) {
        uint v = (t >= off) ? psum[t - off] : 0u;
        __syncthreads();
        psum[t] += v;
        __syncthreads();
    }
    counts[(size_t)b * SLICES + t] = rowoff[b] + psum[t] - c;  // exclusive
}

// ---------------- K3: chunked counting-sort scatter + virial ---------
// entry (uint2): x=h2(dEx,dEy)  y=h(dEz) | local<<16
// j-entries: sign-flipped dE (fp16 sign-bit XOR).
// Staged in LDS bucket-sorted per chunk, then coalesced copy-out: keeps the
// L2 write-set tiny so lines are written ~once (v10's direct scatter had
// 3.6x write amplification). Virial: native ds_add into per-image bins.
__global__ __launch_bounds__(1024) void k_scatter(
    const float* __restrict__ edge_diff, const float* __restrict__ dE_ddiff,
    const int2* __restrict__ edge_idx, const int* __restrict__ image_idx,
    const uint* __restrict__ offsets, uint2* __restrict__ entries,
    float* __restrict__ vpart,
    int n_edges, int es, int nb, int nv)
{
    __shared__ uint2 s_ent[CHUNK_ENT];   // 32 KB
    __shared__ uint  s_dst[CHUNK_ENT];   // 16 KB
    __shared__ uint  cnt[NBCAP];         // 4 KB
    __shared__ uint  base[NBCAP];        // 4 KB
    __shared__ uint  gcur[NBCAP];        // 4 KB
    __shared__ float v_lds[NVMAX];       // 4.5 KB
    __shared__ uint  wtot[16], wpre[16];

    const int s    = blockIdx.x;
    const int tid  = threadIdx.x;
    const int lane = tid & 63;
    const int wid  = tid >> 6;

    gcur[tid] = (tid < nb) ? offsets[(size_t)tid * SLICES + s] : 0u;
    for (int t = tid; t < nv; t += 1024) v_lds[t] = 0.f;
    __syncthreads();

    const int e0 = s * es;
    const int e1 = min(n_edges, e0 + es);

    for (int clo = e0; clo < e1; clo += CHUNK_E) {
        const int chi  = min(e1, clo + CHUNK_E);
        const int nent = 2 * (chi - clo);

        cnt[tid] = 0;
        __syncthreads();

        // phase 1: load, pack, rank, virial
        uint2 ei[2], ej[2];
        uint  bi[2], bj[2], ri[2], rj[2];
        #pragma unroll
        for (int k = 0; k < 2; ++k) {
            const int e = clo + (k << 10) + tid;
            bi[k] = 0xffffffffu;
            if (e < chi) {
                const int2 ij = edge_idx[e];
                const float dx = dE_ddiff[3*e + 0];
                const float dy = dE_ddiff[3*e + 1];
                const float dz = dE_ddiff[3*e + 2];
                const uint ai = (uint)ij.x, aj = (uint)ij.y;
                bi[k] = ai >> BASHIFT;
                bj[k] = aj >> BASHIFT;
                const uint mask = (1u << BASHIFT) - 1u;
                const uint dzh = (uint)__half_as_ushort(__float2half_rn(dz));
                ei[k].x = pack_h2(dx, dy);
                ei[k].y = dzh | ((ai & mask) << 16);
                ej[k].x = ei[k].x ^ 0x80008000u;                  // -dx,-dy
                ej[k].y = (dzh ^ 0x8000u) | ((aj & mask) << 16);  // -dz

                // virial: edge_diff (x) dE, binned by image of atom i
                const float ex = edge_diff[3*e + 0];
                const float ey = edge_diff[3*e + 1];
                const float ez = edge_diff[3*e + 2];
                const int img = image_idx[ij.x];
                float* v = &v_lds[img * 9];
                unsafeAtomicAdd(&v[0], ex*dx); unsafeAtomicAdd(&v[1], ex*dy); unsafeAtomicAdd(&v[2], ex*dz);
                unsafeAtomicAdd(&v[3], ey*dx); unsafeAtomicAdd(&v[4], ey*dy); unsafeAtomicAdd(&v[5], ey*dz);
                unsafeAtomicAdd(&v[6], ez*dx); unsafeAtomicAdd(&v[7], ez*dy); unsafeAtomicAdd(&v[8], ez*dz);

                ri[k] = atomicAdd(&cnt[bi[k]], 1u);
                rj[k] = atomicAdd(&cnt[bj[k]], 1u);
            }
        }
        __syncthreads();

        // phase 2: two-level wave-shfl exclusive scan of cnt[1024]
        const uint c0 = cnt[tid];
        uint v = c0;
        #pragma unroll
        for (int off = 1; off < 64; off <<= 1) {
            const uint n = __shfl_up(v, off, 64);
            if (lane >= off) v += n;
        }
        if (lane == 63) wtot[wid] = v;
        __syncthreads();
        if (wid == 0) {
            uint t2 = (lane < 16) ? wtot[lane] : 0u;
            #pragma unroll
            for (int off = 1; off < 16; off <<= 1) {
                const uint n = __shfl_up(t2, off, 64);
                if (lane >= off) t2 += n;
            }
            if (lane < 16) wpre[lane] = t2 - wtot[lane];
        }
        __syncthreads();
        base[tid] = v - c0 + wpre[wid];
        __syncthreads();

        // phase 3: place into staging, bucket-sorted, with global dest
        #pragma unroll
        for (int k = 0; k < 2; ++k) {
            if (bi[k] != 0xffffffffu) {
                const uint pi = base[bi[k]] + ri[k];
                s_ent[pi] = ei[k];
                s_dst[pi] = gcur[bi[k]] + ri[k];
                const uint pj = base[bj[k]] + rj[k];
                s_ent[pj] = ej[k];
                s_dst[pj] = gcur[bj[k]] + rj[k];
            }
        }
        __syncthreads();

        // phase 4: coalesced copy-out
        for (int t = tid; t < nent; t += 1024)
            entries[s_dst[t]] = s_ent[t];

        // phase 5: advance cursors
        gcur[tid] += cnt[tid];
        __syncthreads();
    }

    __syncthreads();
    for (int t = tid; t < nv; t += 1024)
        vpart[(size_t)s * nv + t] = v_lds[t];            // coalesced partials
}

// ---------------- K3b: reduce virial partials (plain stores) ----------
__global__ __launch_bounds__(128) void k_vreduce(
    const float* __restrict__ vpart, float* __restrict__ virial, int nv)
{
    const int t = blockIdx.x * 128 + threadIdx.x;
    if (t >= nv) return;
    float acc = 0.f;
    #pragma unroll 8
    for (int b = 0; b < SLICES; ++b) acc += vpart[(size_t)b * nv + t];
    virial[t] = acc;
}

// ---------------- K4: gather -> forces ----------------
__device__ __forceinline__ void proc_entry(uint2 e, float* wt) {
    const float2 dxy = __half22float2(*(const __half2*)&e.x);
    const float  dz  = __half2float(__ushort_as_half((ushort)(e.y & 0xffffu)));
    const uint local = (e.y >> 16) & 0xffu;
    unsafeAtomicAdd(&wt[local*3 + 0], dxy.x);
    unsafeAtomicAdd(&wt[local*3 + 1], dxy.y);
    unsafeAtomicAdd(&wt[local*3 + 2], dz);
}

__global__ __launch_bounds__(GT) void k_gather(
    const uint2* __restrict__ entries, const uint* __restrict__ offsets,
    float* __restrict__ forces,
    int n_atoms, int nb, uint total)
{
    __shared__ float tile[GW][3 << BASHIFT];   // 8 waves x 3 KB

    const int q    = blockIdx.x;
    const int tid  = threadIdx.x;
    const int wid  = tid >> 6;
    const int batom = q << BASHIFT;

    for (int t = tid; t < GW * (3 << BASHIFT); t += GT)
        ((float*)tile)[t] = 0.f;
    __syncthreads();

    const uint beg = offsets[(size_t)q * SLICES];
    const uint end = (q + 1 < nb) ? offsets[(size_t)(q + 1) * SLICES] : total;
    float* wt = tile[wid];

    // 4-wide unrolled main loop: 4 outstanding 8B loads per thread
    const uint step = GT;
    uint k = beg + tid;
    while (k + 3u * step < end) {
        const uint2 e0 = entries[k];
        const uint2 e1 = entries[k +      step];
        const uint2 e2 = entries[k + 2u * step];
        const uint2 e3 = entries[k + 3u * step];
        proc_entry(e0, wt);
        proc_entry(e1, wt);
        proc_entry(e2, wt);
        proc_entry(e3, wt);
        k += 4u * step;
    }
    for (; k < end; k += step)
        proc_entry(entries[k], wt);

    __syncthreads();

    const int nvalid = min(n_atoms - batom, 1 << BASHIFT);
    const int lim3 = nvalid * 3;
    for (int t = tid; t < lim3; t += GT) {
        float ssum = 0.f;
        #pragma unroll
        for (int w = 0; w < GW; ++w) ssum += tile[w][t];
        forces[(size_t)batom * 3 + t] = ssum;
    }
}

// ---------------- K5: stress ----------------
__global__ void k_stress(const float* __restrict__ cell,
                         const float* __restrict__ virial,
                         float* __restrict__ stress, int n_images)
{
    const int t = blockIdx.x * blockDim.x + threadIdx.x;
    if (t >= n_images * 9) return;
    const float* c = &cell[(t / 9) * 9];
    const float crx = c[4]*c[8] - c[5]*c[7];
    const float cry = c[5]*c[6] - c[3]*c[8];
    const float crz = c[3]*c[7] - c[4]*c[6];
    const float vol = c[0]*crx + c[1]*cry + c[2]*crz;
    stress[t] = virial[t] * (-1.0f / vol);
}

// ---------------- fallback (round-1) path ----------------
__global__ __launch_bounds__(256) void edge_kernel_fb(
    const float* __restrict__ edge_diff, const float* __restrict__ dE_ddiff,
    const int2* __restrict__ edge_idx, const int* __restrict__ image_idx,
    float* __restrict__ forces, float* __restrict__ virial,
    int n_edges, int n_images)
{
    extern __shared__ float lds_v[];
    const int nv = n_images * 9;
    for (int t = threadIdx.x; t < nv; t += blockDim.x) lds_v[t] = 0.f;
    __syncthreads();
    const int stride = gridDim.x * blockDim.x;
    for (int e = blockIdx.x * blockDim.x + threadIdx.x; e < n_edges; e += stride) {
        const int2 ij = edge_idx[e];
        const int i = ij.x, j = ij.y;
        const float dx = dE_ddiff[3*e+0], dy = dE_ddiff[3*e+1], dz = dE_ddiff[3*e+2];
        unsafeAtomicAdd(&forces[3*i+0],  dx);
        unsafeAtomicAdd(&forces[3*i+1],  dy);
        unsafeAtomicAdd(&forces[3*i+2],  dz);
        unsafeAtomicAdd(&forces[3*j+0], -dx);
        unsafeAtomicAdd(&forces[3*j+1], -dy);
        unsafeAtomicAdd(&forces[3*j+2], -dz);
        const float ex = edge_diff[3*e+0], ey = edge_diff[3*e+1], ez = edge_diff[3*e+2];
        float* v = &lds_v[image_idx[i] * 9];
        unsafeAtomicAdd(&v[0], ex*dx); unsafeAtomicAdd(&v[1], ex*dy); unsafeAtomicAdd(&v[2], ex*dz);
        unsafeAtomicAdd(&v[3], ey*dx); unsafeAtomicAdd(&v[4], ey*dy); unsafeAtomicAdd(&v[5], ey*dz);
        unsafeAtomicAdd(&v[6], ez*dx); unsafeAtomicAdd(&v[7], ez*dy); unsafeAtomicAdd(&v[8], ez*dz);
    }
    __syncthreads();
    for (int t = threadIdx.x; t < nv; t += blockDim.x) {
        const float val = lds_v[t];
        if (val != 0.f) unsafeAtomicAdd(&virial[t], val);
    }
}

extern "C" void kernel_launch(void* const* d_in, const int* in_sizes, int n_in,
                              void* d_out, int out_size, void* d_ws, size_t ws_size,
                              hipStream_t stream)
{
    const float* edge_diff = (const float*)d_in[0];
    const float* dE_ddiff  = (const float*)d_in[1];
    const float* cell      = (const float*)d_in[2];
    const int2*  edge_idx  = (const int2*)d_in[3];
    const int*   image_idx = (const int*)d_in[4];

    const int n_edges  = in_sizes[0] / 3;
    const int n_images = in_sizes[2] / 9;
    const int n_atoms  = in_sizes[4];
    const int nv       = n_images * 9;

    float* out    = (float*)d_out;
    float* forces = out;
    float* virial = out + (size_t)n_atoms * 3;
    float* stress = virial + nv;

    const int nb = (n_atoms + (1 << BASHIFT) - 1) >> BASHIFT;
    const int es = (n_edges + SLICES - 1) / SLICES;
    const uint total = (uint)(2 * (size_t)n_edges);

    const size_t entries_bytes = (size_t)total * sizeof(uint2);
    const size_t counts_bytes  = (size_t)nb * SLICES * sizeof(uint);
    const size_t aux_bytes     = 2 * (size_t)NBCAP * sizeof(uint);
    const size_t vpart_bytes   = (size_t)SLICES * NVMAX * sizeof(float);
    const size_t need = entries_bytes + counts_bytes + aux_bytes + vpart_bytes;

    if (ws_size >= need && nb <= NBCAP && nv <= NVMAX) {
        uint2* entries = (uint2*)d_ws;
        uint*  offsets = (uint*)((char*)d_ws + entries_bytes);
        uint*  rowsum  = offsets + (size_t)nb * SLICES;
        uint*  rowoff  = rowsum + NBCAP;
        float* vpart   = (float*)(rowoff + NBCAP);

        k_count<<<SLICES, 1024, 0, stream>>>(edge_idx, offsets, n_edges, es, nb);
        k_rowsum<<<nb, SLICES, 0, stream>>>(offsets, rowsum);
        k_scan_rows<<<1, 1024, 0, stream>>>(rowsum, rowoff, nb);
        k_rowscan<<<nb, SLICES, 0, stream>>>(offsets, rowoff);
        k_scatter<<<SLICES, 1024, 0, stream>>>(edge_diff, dE_ddiff, edge_idx, image_idx,
                                               offsets, entries, vpart,
                                               n_edges, es, nb, nv);
        k_vreduce<<<(nv + 127) / 128, 128, 0, stream>>>(vpart, virial, nv);
        k_gather<<<nb, GT, 0, stream>>>(entries, offsets, forces, n_atoms, nb, total);
        k_stress<<<(nv + 255) / 256, 256, 0, stream>>>(cell, virial, stress, n_images);
    } else {
        hipMemsetAsync(out, 0, ((size_t)n_atoms * 3 + nv) * sizeof(float), stream);
        edge_kernel_fb<<<2048, 256, nv * sizeof(float), stream>>>(
            edge_diff, dE_ddiff, edge_idx, image_idx, forces, virial, n_edges, n_images);
        k_stress<<<(nv + 255) / 256, 256, 0, stream>>>(cell, virial, stress, n_images);
    }
}

// Round 6
// 764.543 us; speedup vs baseline: 1.0330x; 1.0330x over previous
//
#include <hip/hip_runtime.h>
#include <hip/hip_fp16.h>

// Output layout (flat): forces[n_atoms*3] | virial[n_images*9] | stress[n_images*9]
//
// v12: direct zero-barrier scatter (v10 form) + bucket coarsening to kill the
// write amplification: BASHIFT 8->10 (1024-atom buckets, nb=196) shrinks the
// open-window write-set to 128 blk/XCD x 196 x 64B = 1.6 MB < 4 MB L2, so
// entry lines drain once (v10 @ nb=782: 12.8 MB -> 3.6x write blowup; v11's
// chunked fix of that cost 355 us in barriers/LDS round-trips regardless of
// virial -- v8 vs v11 isolated that). Gather: 12 KB block tile per bucket,
// 4 range-splits/bucket (784 blocks), merge via global unsafeAtomicAdd into
// zeroed forces. Virial: native ds_add partials in scatter + k_vreduce
// (v10/v11-verified). SLICES=1024 x 512 threads for count/scatter.

typedef unsigned int uint;
typedef unsigned short ushort;

#define SLICES  1024        // count/scatter blocks (512 threads each)
#define BASHIFT 10          // 1024 atoms per bucket
#define NBCAP   256         // max buckets (n_atoms <= 256k)
#define NVMAX   1152        // n_images*9 cap
#define GT      512         // gather block size
#define GSPLIT  4           // gather blocks per bucket
#define BATOMS  (1 << BASHIFT)

__device__ __forceinline__ uint pack_h2(float a, float b) {
    const __half2 h = __floats2half2_rn(a, b);
    return *(const uint*)&h;
}

// ---------------- K1: per-(slice,bucket) histogram ----------------
__global__ __launch_bounds__(512) void k_count(
    const int2* __restrict__ edge_idx, uint* __restrict__ counts,
    int n_edges, int es, int nb)
{
    __shared__ uint hist[NBCAP];
    for (int t = threadIdx.x; t < nb; t += blockDim.x) hist[t] = 0;
    __syncthreads();
    const int s  = blockIdx.x;
    const int e0 = s * es;
    const int e1 = min(n_edges, e0 + es);
    for (int e = e0 + threadIdx.x; e < e1; e += blockDim.x) {
        const int2 ij = edge_idx[e];
        atomicAdd(&hist[((uint)ij.x) >> BASHIFT], 1u);
        atomicAdd(&hist[((uint)ij.y) >> BASHIFT], 1u);
    }
    __syncthreads();
    for (int b = threadIdx.x; b < nb; b += blockDim.x)
        counts[(size_t)b * SLICES + s] = hist[b];   // bucket-major
}

// ---------------- K2a: row sums ----------------
__global__ __launch_bounds__(SLICES) void k_rowsum(
    const uint* __restrict__ counts, uint* __restrict__ rowsum)
{
    __shared__ uint red[SLICES];
    const int b = blockIdx.x;
    red[threadIdx.x] = counts[(size_t)b * SLICES + threadIdx.x];
    __syncthreads();
    for (int off = SLICES / 2; off > 0; off >>= 1) {
        if (threadIdx.x < off) red[threadIdx.x] += red[threadIdx.x + off];
        __syncthreads();
    }
    if (threadIdx.x == 0) rowsum[b] = red[0];
}

// ---------------- K2b: exclusive scan of row sums ----------------
__global__ __launch_bounds__(1024) void k_scan_rows(
    const uint* __restrict__ rowsum, uint* __restrict__ rowoff, int nb)
{
    __shared__ uint psum[1024];
    const int t = threadIdx.x;
    psum[t] = (t < nb) ? rowsum[t] : 0u;
    __syncthreads();
    for (int off = 1; off < 1024; off <<= 1) {
        uint v = (t >= off) ? psum[t - off] : 0u;
        __syncthreads();
        psum[t] += v;
        __syncthreads();
    }
    if (t < nb) rowoff[t] = (t == 0) ? 0u : psum[t - 1];
}

// ---------------- K2c: per-row exclusive scan + global offset ----------
__global__ __launch_bounds__(SLICES) void k_rowscan(
    uint* __restrict__ counts, const uint* __restrict__ rowoff)
{
    __shared__ uint psum[SLICES];
    const int b = blockIdx.x;
    const int t = threadIdx.x;
    const uint c = counts[(size_t)b * SLICES + t];
    psum[t] = c;
    __syncthreads();
    for (int off = 1; off < SLICES; off <<= 1) {
        uint v = (t >= off) ? psum[t - off] : 0u;
        __syncthreads();
        psum[t] += v;
        __syncthreads();
    }
    counts[(size_t)b * SLICES + t] = rowoff[b] + psum[t] - c;  // exclusive
}

// ---------------- K3: direct counting-sort scatter + virial ------------
// entry (uint2): x=h2(dEx,dEy)  y=h(dEz) | local<<16   (local < 1024)
// j-entries: sign-flipped dE (fp16 sign-bit XOR).
// Zero barriers in the main loop. Per-(bucket,slice) destination segments
// are exclusive to this block; LDS uint cursors hand out absolute slots.
// With nb=196, the XCD-wide open-line set is ~1.6 MB < 4 MB L2, so lines
// drain once (this was 12.8 MB / 3.6x write blowup at nb=782 in v10).
__global__ __launch_bounds__(512) void k_scatter(
    const float* __restrict__ edge_diff, const float* __restrict__ dE_ddiff,
    const int2* __restrict__ edge_idx, const int* __restrict__ image_idx,
    const uint* __restrict__ offsets, uint2* __restrict__ entries,
    float* __restrict__ vpart,
    int n_edges, int es, int nb, int nv)
{
    __shared__ uint  gcur[NBCAP];
    __shared__ float v_lds[NVMAX];
    const int s   = blockIdx.x;
    const int tid = threadIdx.x;
    for (int t = tid; t < nb; t += blockDim.x)
        gcur[t] = offsets[(size_t)t * SLICES + s];
    for (int t = tid; t < nv; t += blockDim.x) v_lds[t] = 0.f;
    __syncthreads();

    const int e0 = s * es;
    const int e1 = min(n_edges, e0 + es);
    const uint mask = (1u << BASHIFT) - 1u;

    for (int e = e0 + tid; e < e1; e += blockDim.x) {
        const int2 ij = edge_idx[e];
        const float dx = dE_ddiff[3*e + 0];
        const float dy = dE_ddiff[3*e + 1];
        const float dz = dE_ddiff[3*e + 2];
        const uint ai = (uint)ij.x, aj = (uint)ij.y;
        const uint dzh = (uint)__half_as_ushort(__float2half_rn(dz));
        uint2 ei, ej;
        ei.x = pack_h2(dx, dy);
        ei.y = dzh | ((ai & mask) << 16);
        ej.x = ei.x ^ 0x80008000u;                       // -dx, -dy
        ej.y = (dzh ^ 0x8000u) | ((aj & mask) << 16);    // -dz

        const uint di = atomicAdd(&gcur[ai >> BASHIFT], 1u);
        entries[di] = ei;
        const uint dj = atomicAdd(&gcur[aj >> BASHIFT], 1u);
        entries[dj] = ej;

        // virial: edge_diff (x) dE, binned by image of atom i (native ds_add)
        const float ex = edge_diff[3*e + 0];
        const float ey = edge_diff[3*e + 1];
        const float ez = edge_diff[3*e + 2];
        const int img = image_idx[ij.x];
        float* v = &v_lds[img * 9];
        unsafeAtomicAdd(&v[0], ex*dx); unsafeAtomicAdd(&v[1], ex*dy); unsafeAtomicAdd(&v[2], ex*dz);
        unsafeAtomicAdd(&v[3], ey*dx); unsafeAtomicAdd(&v[4], ey*dy); unsafeAtomicAdd(&v[5], ey*dz);
        unsafeAtomicAdd(&v[6], ez*dx); unsafeAtomicAdd(&v[7], ez*dy); unsafeAtomicAdd(&v[8], ez*dz);
    }
    __syncthreads();
    for (int t = tid; t < nv; t += blockDim.x)
        vpart[(size_t)s * nv + t] = v_lds[t];            // coalesced partials
}

// ---------------- K3b: reduce virial partials (plain stores) ----------
__global__ __launch_bounds__(128) void k_vreduce(
    const float* __restrict__ vpart, float* __restrict__ virial, int nv)
{
    const int t = blockIdx.x * 128 + threadIdx.x;
    if (t >= nv) return;
    float acc = 0.f;
    #pragma unroll 8
    for (int b = 0; b < SLICES; ++b) acc += vpart[(size_t)b * nv + t];
    virial[t] = acc;
}

// ---------------- K4: gather -> forces (4 splits per bucket) ----------
__device__ __forceinline__ void proc_entry(uint2 e, float* tile) {
    const float2 dxy = __half22float2(*(const __half2*)&e.x);
    const float  dz  = __half2float(__ushort_as_half((ushort)(e.y & 0xffffu)));
    const uint local = (e.y >> 16) & (BATOMS - 1u);
    unsafeAtomicAdd(&tile[local*3 + 0], dxy.x);
    unsafeAtomicAdd(&tile[local*3 + 1], dxy.y);
    unsafeAtomicAdd(&tile[local*3 + 2], dz);
}

__global__ __launch_bounds__(GT) void k_gather(
    const uint2* __restrict__ entries, const uint* __restrict__ offsets,
    float* __restrict__ forces /* zeroed */,
    int n_atoms, int nb, uint total)
{
    __shared__ float tile[3 * BATOMS];   // 12 KB block-level

    const int q     = blockIdx.x / GSPLIT;
    const int split = blockIdx.x - q * GSPLIT;
    const int tid   = threadIdx.x;
    const int batom = q << BASHIFT;

    for (int t = tid; t < 3 * BATOMS; t += GT) tile[t] = 0.f;
    __syncthreads();

    const uint beg = offsets[(size_t)q * SLICES];
    const uint end = (q + 1 < nb) ? offsets[(size_t)(q + 1) * SLICES] : total;
    const uint len = end - beg;
    const uint s0  = beg + (uint)(((unsigned long long)len *  split     ) / GSPLIT);
    const uint s1  = beg + (uint)(((unsigned long long)len * (split + 1)) / GSPLIT);

    // 4-wide unrolled main loop: 4 outstanding 8B loads per thread
    const uint step = GT;
    uint k = s0 + tid;
    while (k + 3u * step < s1) {
        const uint2 e0 = entries[k];
        const uint2 e1 = entries[k +      step];
        const uint2 e2 = entries[k + 2u * step];
        const uint2 e3 = entries[k + 3u * step];
        proc_entry(e0, tile);
        proc_entry(e1, tile);
        proc_entry(e2, tile);
        proc_entry(e3, tile);
        k += 4u * step;
    }
    for (; k < s1; k += step)
        proc_entry(entries[k], tile);

    __syncthreads();

    const int nvalid = min(n_atoms - batom, BATOMS);
    const int lim3 = nvalid * 3;
    for (int t = tid; t < lim3; t += GT) {
        const float val = tile[t];
        if (val != 0.f) unsafeAtomicAdd(&forces[(size_t)batom * 3 + t], val);
    }
}

// ---------------- K5: stress ----------------
__global__ void k_stress(const float* __restrict__ cell,
                         const float* __restrict__ virial,
                         float* __restrict__ stress, int n_images)
{
    const int t = blockIdx.x * blockDim.x + threadIdx.x;
    if (t >= n_images * 9) return;
    const float* c = &cell[(t / 9) * 9];
    const float crx = c[4]*c[8] - c[5]*c[7];
    const float cry = c[5]*c[6] - c[3]*c[8];
    const float crz = c[3]*c[7] - c[4]*c[6];
    const float vol = c[0]*crx + c[1]*cry + c[2]*crz;
    stress[t] = virial[t] * (-1.0f / vol);
}

// ---------------- fallback (round-1) path ----------------
__global__ __launch_bounds__(256) void edge_kernel_fb(
    const float* __restrict__ edge_diff, const float* __restrict__ dE_ddiff,
    const int2* __restrict__ edge_idx, const int* __restrict__ image_idx,
    float* __restrict__ forces, float* __restrict__ virial,
    int n_edges, int n_images)
{
    extern __shared__ float lds_v[];
    const int nv = n_images * 9;
    for (int t = threadIdx.x; t < nv; t += blockDim.x) lds_v[t] = 0.f;
    __syncthreads();
    const int stride = gridDim.x * blockDim.x;
    for (int e = blockIdx.x * blockDim.x + threadIdx.x; e < n_edges; e += stride) {
        const int2 ij = edge_idx[e];
        const int i = ij.x, j = ij.y;
        const float dx = dE_ddiff[3*e+0], dy = dE_ddiff[3*e+1], dz = dE_ddiff[3*e+2];
        unsafeAtomicAdd(&forces[3*i+0],  dx);
        unsafeAtomicAdd(&forces[3*i+1],  dy);
        unsafeAtomicAdd(&forces[3*i+2],  dz);
        unsafeAtomicAdd(&forces[3*j+0], -dx);
        unsafeAtomicAdd(&forces[3*j+1], -dy);
        unsafeAtomicAdd(&forces[3*j+2], -dz);
        const float ex = edge_diff[3*e+0], ey = edge_diff[3*e+1], ez = edge_diff[3*e+2];
        float* v = &lds_v[image_idx[i] * 9];
        unsafeAtomicAdd(&v[0], ex*dx); unsafeAtomicAdd(&v[1], ex*dy); unsafeAtomicAdd(&v[2], ex*dz);
        unsafeAtomicAdd(&v[3], ey*dx); unsafeAtomicAdd(&v[4], ey*dy); unsafeAtomicAdd(&v[5], ey*dz);
        unsafeAtomicAdd(&v[6], ez*dx); unsafeAtomicAdd(&v[7], ez*dy); unsafeAtomicAdd(&v[8], ez*dz);
    }
    __syncthreads();
    for (int t = threadIdx.x; t < nv; t += blockDim.x) {
        const float val = lds_v[t];
        if (val != 0.f) unsafeAtomicAdd(&virial[t], val);
    }
}

extern "C" void kernel_launch(void* const* d_in, const int* in_sizes, int n_in,
                              void* d_out, int out_size, void* d_ws, size_t ws_size,
                              hipStream_t stream)
{
    const float* edge_diff = (const float*)d_in[0];
    const float* dE_ddiff  = (const float*)d_in[1];
    const float* cell      = (const float*)d_in[2];
    const int2*  edge_idx  = (const int2*)d_in[3];
    const int*   image_idx = (const int*)d_in[4];

    const int n_edges  = in_sizes[0] / 3;
    const int n_images = in_sizes[2] / 9;
    const int n_atoms  = in_sizes[4];
    const int nv       = n_images * 9;

    float* out    = (float*)d_out;
    float* forces = out;
    float* virial = out + (size_t)n_atoms * 3;
    float* stress = virial + nv;

    const int nb = (n_atoms + BATOMS - 1) >> BASHIFT;
    const int es = (n_edges + SLICES - 1) / SLICES;
    const uint total = (uint)(2 * (size_t)n_edges);

    const size_t entries_bytes = (size_t)total * sizeof(uint2);
    const size_t counts_bytes  = (size_t)NBCAP * SLICES * sizeof(uint);
    const size_t aux_bytes     = 2 * (size_t)NBCAP * sizeof(uint);
    const size_t vpart_bytes   = (size_t)SLICES * NVMAX * sizeof(float);
    const size_t need = entries_bytes + counts_bytes + aux_bytes + vpart_bytes;

    if (ws_size >= need && nb <= NBCAP && nv <= NVMAX) {
        uint2* entries = (uint2*)d_ws;
        uint*  offsets = (uint*)((char*)d_ws + entries_bytes);
        uint*  rowsum  = offsets + (size_t)NBCAP * SLICES;
        uint*  rowoff  = rowsum + NBCAP;
        float* vpart   = (float*)(rowoff + NBCAP);

        hipMemsetAsync(forces, 0, (size_t)n_atoms * 3 * sizeof(float), stream);

        k_count<<<SLICES, 512, 0, stream>>>(edge_idx, offsets, n_edges, es, nb);
        k_rowsum<<<nb, SLICES, 0, stream>>>(offsets, rowsum);
        k_scan_rows<<<1, 1024, 0, stream>>>(rowsum, rowoff, nb);
        k_rowscan<<<nb, SLICES, 0, stream>>>(offsets, rowoff);
        k_scatter<<<SLICES, 512, 0, stream>>>(edge_diff, dE_ddiff, edge_idx, image_idx,
                                              offsets, entries, vpart,
                                              n_edges, es, nb, nv);
        k_vreduce<<<(nv + 127) / 128, 128, 0, stream>>>(vpart, virial, nv);
        k_gather<<<nb * GSPLIT, GT, 0, stream>>>(entries, offsets, forces,
                                                 n_atoms, nb, total);
        k_stress<<<(nv + 255) / 256, 256, 0, stream>>>(cell, virial, stress, n_images);
    } else {
        hipMemsetAsync(out, 0, ((size_t)n_atoms * 3 + nv) * sizeof(float), stream);
        edge_kernel_fb<<<2048, 256, nv * sizeof(float), stream>>>(
            edge_diff, dE_ddiff, edge_idx, image_idx, forces, virial, n_edges, n_images);
        k_stress<<<(nv + 255) / 256, 256, 0, stream>>>(cell, virial, stress, n_images);
    }
}